// Round 3
// baseline (188.779 us; speedup 1.0000x reference)
//
#include <hip/hip_runtime.h>

// VQ-VAE quantizer: x[32][64][64][64] f32 NCHW, embed[1024][64] f32
// out: z_q (8388608 f32, NCHW) ++ loss (1 f32),  loss = 1.25*mean((z_q-z)^2)
//
// Structure: wave owns 256 codes RESIDENT in VGPRs (32 bf16x8 A-frags, loaded
// once); block processes 4 h-consecutive (b,h) tiles with double-buffered LDS
// z-tile. Inner loop: pure MFMA + packed-key argmax (no global loads).

#define TOTAL_ELEMS 8388608
#define LOSS_SCALE (1.25f / 8388608.f)

typedef float  f32x4  __attribute__((ext_vector_type(4)));
typedef __bf16 bf16x8 __attribute__((ext_vector_type(8)));
typedef unsigned int u32x4 __attribute__((ext_vector_type(4)));

static __device__ __forceinline__ unsigned short f2bf(float f) {
    unsigned int u = __float_as_uint(f);
    u += 0x7FFFu + ((u >> 16) & 1u);   // round-to-nearest-even
    return (unsigned short)(u >> 16);
}

// ---- prep: embed f32 -> bf16 copy + c0 = 0.25 - 0.5*||e||^2 + zero loss ----
__global__ void vq_prep(const float* __restrict__ embed,
                        unsigned short* __restrict__ eb,
                        float* __restrict__ c0,
                        float* __restrict__ loss_slot) {
    int t   = blockIdx.x * 256 + threadIdx.x;   // 0..4095
    int row = t >> 2, qd = t & 3;
    const float* src = embed + row * 64 + qd * 16;
    float s = 0.f;
    unsigned short tmp[16];
#pragma unroll
    for (int i = 0; i < 4; i++) {
        f32x4 v = *(const f32x4*)(src + i * 4);
#pragma unroll
        for (int j = 0; j < 4; j++) {
            float f = v[j];
            s += f * f;
            tmp[i * 4 + j] = f2bf(f);
        }
    }
    u32x4 w0, w1;
#pragma unroll
    for (int i = 0; i < 4; i++) {
        w0[i] = (unsigned)tmp[2*i]   | ((unsigned)tmp[2*i+1] << 16);
        w1[i] = (unsigned)tmp[8+2*i] | ((unsigned)tmp[8+2*i+1] << 16);
    }
    u32x4* dst = (u32x4*)(eb + row * 64 + qd * 16);
    dst[0] = w0; dst[1] = w1;
    s += __shfl_xor(s, 1);
    s += __shfl_xor(s, 2);
    if (qd == 0) c0[row] = 0.25f - 0.5f * s;    // MFMA C-init: acc = z.e + c0 > 0
    if (t == 0) *loss_slot = 0.f;
}

// argmin dist == argmax acc (acc = z.e + 0.25 - ||e||^2/2, strictly positive)
// key = (bits(acc) & ~1023) | (1023 - code)  -> pure u32 max chain
__global__ __launch_bounds__(256, 2) void vq_main(
    const float* __restrict__ x,
    const float* __restrict__ embed,            // f32, for exact gather
    const unsigned short* __restrict__ eb,      // bf16
    const float* __restrict__ c0,               // f32 per-code C-init
    float* __restrict__ out,
    float* __restrict__ loss) {

    __shared__ unsigned short tile[2][64 * 64]; // [pos][k] bf16, swizzled, 2x8KB
    __shared__ float c0l[1024];                 // codebook C-init, 4 KB
    __shared__ unsigned int wkey[4][64];
    __shared__ int   idxf[64];
    __shared__ float lpart[4];

    const int t    = threadIdx.x;
    const int wv   = t >> 6, lane = t & 63;
    const int l15  = lane & 15, lq = lane >> 4;
    const int k0   = lq * 8;
    const int cb   = wv * 256;
    const int c    = t & 63, q = t >> 6;        // staging role: channel c, w-seg q

    // ---- c0 -> LDS (4 KB) ----
    *(f32x4*)(c0l + t * 4) = *(const f32x4*)(c0 + t * 4);

    // ---- A-frag prologue: wave's 256 codes resident (128 VGPR) ----
    bf16x8 A0[16], A1[16];
#pragma unroll
    for (int mt = 0; mt < 16; mt++) {
        int mrow = cb + mt * 16 + l15;
        A0[mt] = *(const bf16x8*)(eb + mrow * 64 + k0);
        A1[mt] = *(const bf16x8*)(eb + mrow * 64 + 32 + k0);
    }

    const int tile_base = blockIdx.x * 4;       // 4 h-consecutive tiles
    // ---- stage tile 0 into buf 0 ----
    {
        const int tl = tile_base;
        const int b = tl >> 6, h = tl & 63;
        const size_t base = (size_t)b * 262144 + (size_t)h * 64;
#pragma unroll
        for (int i = 0; i < 4; i++) {
            int w0 = q * 16 + i * 4;
            f32x4 v = *(const f32x4*)(x + base + (size_t)c * 4096 + w0);
#pragma unroll
            for (int j = 0; j < 4; j++) {
                int w = w0 + j;
                int byteoff = w * 128 + ((c * 2) ^ ((w & 7) << 4));
                *(unsigned short*)((char*)tile[0] + byteoff) = f2bf(v[j]);
            }
        }
    }
    float lsum = 0.f;
    const int inv_base = 1023 - cb - lq * 4;
    __syncthreads();

#pragma unroll
    for (int tt = 0; tt < 4; tt++) {
        const int cur = tt & 1;
        const int tl  = tile_base + tt;
        const int b   = tl >> 6, h = tl & 63;
        const size_t base = (size_t)b * 262144 + (size_t)h * 64;

        // issue next tile's global loads early (latency hides under MFMA)
        f32x4 xs[4];
        if (tt < 3) {
            const size_t nbase = base + 64;     // next h, same b
#pragma unroll
            for (int i = 0; i < 4; i++)
                xs[i] = *(const f32x4*)(x + nbase + (size_t)c * 4096 + q * 16 + i * 4);
        }

        // B-frags from tile[cur]
        bf16x8 bfr[4][2];
#pragma unroll
        for (int nt = 0; nt < 4; nt++) {
            int pos = nt * 16 + l15;
            int rb  = pos * 128;
            int sw  = (pos & 7) << 4;
            bfr[nt][0] = *(const bf16x8*)((const char*)tile[cur] + rb + ((k0 * 2) ^ sw));
            bfr[nt][1] = *(const bf16x8*)((const char*)tile[cur] + rb + ((64 + k0 * 2) ^ sw));
        }

        // ---- pure-compute inner loop: 128 MFMA + 2-op key updates ----
        unsigned int key[4] = {0u, 0u, 0u, 0u};
#pragma unroll
        for (int mt = 0; mt < 16; mt++) {
            const f32x4 c0mt = *(const f32x4*)(c0l + cb + mt * 16 + lq * 4);
            const int invm = inv_base - mt * 16;
#pragma unroll
            for (int nt = 0; nt < 4; nt++) {
                f32x4 acc = __builtin_amdgcn_mfma_f32_16x16x32_bf16(A0[mt], bfr[nt][0], c0mt, 0, 0, 0);
                acc = __builtin_amdgcn_mfma_f32_16x16x32_bf16(A1[mt], bfr[nt][1], acc, 0, 0, 0);
                // D: col(l15)=pos-in-tile, row=(lq*4+r)=code-in-chunk
#pragma unroll
                for (int r = 0; r < 4; r++) {
                    unsigned int k2 = (__float_as_uint(acc[r]) & 0xFFFFFC00u)
                                    | (unsigned int)(invm - r);
                    key[nt] = key[nt] > k2 ? key[nt] : k2;
                }
            }
        }

        // ---- wave-level argmax reduce ----
#pragma unroll
        for (int nt = 0; nt < 4; nt++) {
            unsigned int k = key[nt];
            unsigned int o = (unsigned int)__shfl_xor((int)k, 16); k = k > o ? k : o;
            o = (unsigned int)__shfl_xor((int)k, 32);              k = k > o ? k : o;
            if (lane < 16) wkey[wv][nt * 16 + lane] = k;
        }
        __syncthreads();
        if (t < 64) {
            unsigned int k = wkey[0][t];
            unsigned int o1 = wkey[1][t]; k = k > o1 ? k : o1;
            unsigned int o2 = wkey[2][t]; k = k > o2 ? k : o2;
            unsigned int o3 = wkey[3][t]; k = k > o3 ? k : o3;
            idxf[t] = 1023 - (int)(k & 1023u);
        }
        __syncthreads();

        // ---- output: gather z_q (exact f32), write NCHW, loss partial ----
#pragma unroll
        for (int i = 0; i < 4; i++) {
            int w0 = q * 16 + i * 4;
            const size_t off = base + (size_t)c * 4096 + w0;
            f32x4 xv = *(const f32x4*)(x + off);   // L1/L2-hot re-read
            f32x4 ov;
#pragma unroll
            for (int j = 0; j < 4; j++) {
                int idx = idxf[w0 + j];
                float zq = embed[idx * 64 + c];    // coalesced 256B row read
                ov[j] = zq;
                float d = zq - xv[j];
                lsum += d * d;
            }
            *(f32x4*)(out + off) = ov;
        }

        // ---- ds_write next tile into tile[cur^1] ----
        if (tt < 3) {
#pragma unroll
            for (int i = 0; i < 4; i++) {
                int w0 = q * 16 + i * 4;
#pragma unroll
                for (int j = 0; j < 4; j++) {
                    int w = w0 + j;
                    int byteoff = w * 128 + ((c * 2) ^ ((w & 7) << 4));
                    *(unsigned short*)((char*)tile[cur ^ 1] + byteoff) = f2bf(xs[i][j]);
                }
            }
        }
        __syncthreads();
    }

    // ---- block-reduce loss, one atomic per block ----
#pragma unroll
    for (int off = 1; off < 64; off <<= 1) lsum += __shfl_xor(lsum, off);
    if (lane == 0) lpart[wv] = lsum;
    __syncthreads();
    if (t == 0)
        atomicAdd(loss, (lpart[0] + lpart[1] + lpart[2] + lpart[3]) * LOSS_SCALE);
}

extern "C" void kernel_launch(void* const* d_in, const int* in_sizes, int n_in,
                              void* d_out, int out_size, void* d_ws, size_t ws_size,
                              hipStream_t stream) {
    const float* x     = (const float*)d_in[0];
    const float* embed = (const float*)d_in[1];
    unsigned short* eb = (unsigned short*)d_ws;               // 1024*64 bf16 = 128 KB
    float* c0          = (float*)((char*)d_ws + 131072);      // 1024 f32  = 4 KB
    float* out  = (float*)d_out;
    float* loss = out + TOTAL_ELEMS;

    vq_prep<<<16, 256, 0, stream>>>(embed, eb, c0, loss);
    vq_main<<<512, 256, 0, stream>>>(x, embed, eb, c0, out, loss);
}

// Round 4
// 67.675 us; speedup vs baseline: 2.7895x; 2.7895x over previous
//
#include <hip/hip_runtime.h>

// VQ-VAE quantizer: x[32][64][64][64] f32 NCHW, embed[1024][64] f32
// out: z_q (8388608 f32, NCHW) ++ loss (1 f32),  loss = 1.25*mean((z_q-z)^2)
//
// Block = 4 waves = 4 h-rows (256 positions). z staged once in LDS (32 KB),
// B-frags -> VGPR, then the SAME 32 KB holds codebook chunks (4 x 256 codes).
// Inner loop: ds_read A-frags + MFMA + packed-key argmax. Wave owns disjoint
// positions -> argmax fully wave-local. No VGPR-resident codebook (R2/R3
// spilled); stage regs are 32 VGPR transient only.

#define TOTAL_ELEMS 8388608
#define LOSS_SCALE (1.25f / 8388608.f)

typedef float  f32x4  __attribute__((ext_vector_type(4)));
typedef __bf16 bf16x8 __attribute__((ext_vector_type(8)));
typedef unsigned int u32x4 __attribute__((ext_vector_type(4)));

static __device__ __forceinline__ unsigned short f2bf(float f) {
    unsigned int u = __float_as_uint(f);
    u += 0x7FFFu + ((u >> 16) & 1u);   // round-to-nearest-even
    return (unsigned short)(u >> 16);
}

// ---- prep: embed f32 -> bf16 copy + c0 = 0.25 - 0.5*||e||^2 + zero loss ----
__global__ void vq_prep(const float* __restrict__ embed,
                        unsigned short* __restrict__ eb,
                        float* __restrict__ c0,
                        float* __restrict__ loss_slot) {
    int t   = blockIdx.x * 256 + threadIdx.x;   // 0..4095
    int row = t >> 2, qd = t & 3;
    const float* src = embed + row * 64 + qd * 16;
    float s = 0.f;
    unsigned short tmp[16];
#pragma unroll
    for (int i = 0; i < 4; i++) {
        f32x4 v = *(const f32x4*)(src + i * 4);
#pragma unroll
        for (int j = 0; j < 4; j++) {
            float f = v[j];
            s += f * f;
            tmp[i * 4 + j] = f2bf(f);
        }
    }
    u32x4 w0, w1;
#pragma unroll
    for (int i = 0; i < 4; i++) {
        w0[i] = (unsigned)tmp[2*i]   | ((unsigned)tmp[2*i+1] << 16);
        w1[i] = (unsigned)tmp[8+2*i] | ((unsigned)tmp[8+2*i+1] << 16);
    }
    u32x4* dst = (u32x4*)(eb + row * 64 + qd * 16);
    dst[0] = w0; dst[1] = w1;
    s += __shfl_xor(s, 1);
    s += __shfl_xor(s, 2);
    if (qd == 0) c0[row] = 0.25f - 0.5f * s;    // MFMA C-init: acc = z.e + c0 > 0
    if (t == 0) *loss_slot = 0.f;
}

// argmin dist == argmax acc (acc = z.e + 0.25 - ||e||^2/2, strictly positive)
// key = (bits(acc) & ~1023) | (1023 - code)  -> pure u32 max chain
__global__ __launch_bounds__(256, 2) void vq_main(
    const float* __restrict__ x,
    const float* __restrict__ embed,            // f32, for exact gather
    const unsigned short* __restrict__ eb,      // bf16
    const float* __restrict__ c0,               // f32 per-code C-init
    float* __restrict__ out,
    float* __restrict__ loss) {

    __shared__ __align__(16) unsigned char smem[32768]; // z-tile, then cb chunks
    __shared__ float c0l[1024];
    __shared__ int   idxf[256];
    __shared__ float lpart[4];

    const int t    = threadIdx.x;
    const int wv   = t >> 6, lane = t & 63;
    const int l15  = lane & 15, lq = lane >> 4;
    const int c    = lane;                       // channel (staging/epilogue)
    const int hh   = wv;                         // h-row within block

    const int blk = blockIdx.x;                  // 0..511 = 32 b x 16 h-groups
    const int b   = blk >> 4;
    const int h0  = (blk & 15) * 4;
    const size_t xbase = (size_t)b * 262144 + (size_t)h0 * 64;

    // ---- issue codebook chunk 0 loads first (latency hides under z staging) ----
    u32x4 creg[8];
#pragma unroll
    for (int s = 0; s < 8; s++)
        creg[s] = *(const u32x4*)(eb + t * 64 + s * 8);

    // ---- stage z: 4 h-rows -> [pos][k] bf16, XOR-swizzled ----
#pragma unroll
    for (int i = 0; i < 16; i++) {
        int w0 = i * 4;
        f32x4 v = *(const f32x4*)(x + xbase + (size_t)c * 4096 + (size_t)hh * 64 + w0);
#pragma unroll
        for (int j = 0; j < 4; j++) {
            int w = w0 + j;
            int byteoff = (hh * 64 + w) * 128 + ((c * 2) ^ ((w & 7) << 4));
            *(unsigned short*)(smem + byteoff) = f2bf(v[j]);
        }
    }
    // c0 -> LDS (4 KB)
    *(f32x4*)(c0l + t * 4) = *(const f32x4*)(c0 + t * 4);
    __syncthreads();

    // ---- B-frags for this wave's 64 positions (32 VGPR, resident) ----
    bf16x8 bfr[4][2];
#pragma unroll
    for (int nt = 0; nt < 4; nt++) {
        int pos = wv * 64 + nt * 16 + l15;
        int rb  = pos * 128, sw = (pos & 7) << 4;
        bfr[nt][0] = *(const bf16x8*)(smem + rb + ((lq * 16) ^ sw));
        bfr[nt][1] = *(const bf16x8*)(smem + rb + ((64 + lq * 16) ^ sw));
    }
    __syncthreads();                             // z region dead -> reuse for cb

    // ---- write chunk 0 ----
    {
        int rb = t * 128, sw = (t & 7) << 4;
#pragma unroll
        for (int s = 0; s < 8; s++)
            *(u32x4*)(smem + rb + ((s * 16) ^ sw)) = creg[s];
    }
    __syncthreads();

    // ---- 4 chunks x (16 mt x 4 nt x 2 MFMA) ----
    unsigned int key[4] = {0u, 0u, 0u, 0u};
#pragma unroll
    for (int ch = 0; ch < 4; ch++) {
        if (ch < 3) {                            // issue next chunk's loads early
#pragma unroll
            for (int s = 0; s < 8; s++)
                creg[s] = *(const u32x4*)(eb + (ch + 1) * 16384 + t * 64 + s * 8);
        }
        const int invc = 1023 - ch * 256 - lq * 4;
#pragma unroll
        for (int mt = 0; mt < 16; mt++) {
            int rb = (mt * 16 + l15) * 128, sw = (l15 & 7) << 4;
            bf16x8 a0 = *(const bf16x8*)(smem + rb + ((lq * 16) ^ sw));
            bf16x8 a1 = *(const bf16x8*)(smem + rb + ((64 + lq * 16) ^ sw));
            f32x4 c0v = *(const f32x4*)(c0l + ch * 256 + mt * 16 + lq * 4);
            const int invm = invc - mt * 16;
#pragma unroll
            for (int nt = 0; nt < 4; nt++) {
                f32x4 acc = __builtin_amdgcn_mfma_f32_16x16x32_bf16(a0, bfr[nt][0], c0v, 0, 0, 0);
                acc = __builtin_amdgcn_mfma_f32_16x16x32_bf16(a1, bfr[nt][1], acc, 0, 0, 0);
                // D: col(l15)=pos-in-tile, row=(lq*4+r)=code-in-chunk
#pragma unroll
                for (int r = 0; r < 4; r++) {
                    unsigned int k2 = (__float_as_uint(acc[r]) & 0xFFFFFC00u)
                                    | (unsigned int)(invm - r);
                    key[nt] = key[nt] > k2 ? key[nt] : k2;
                }
            }
        }
        if (ch < 3) {
            __syncthreads();                     // all waves done reading chunk
            int rb = t * 128, sw = (t & 7) << 4;
#pragma unroll
            for (int s = 0; s < 8; s++)
                *(u32x4*)(smem + rb + ((s * 16) ^ sw)) = creg[s];
            __syncthreads();
        }
    }

    // ---- wave-local argmax reduce (codes spread over lane^16, lane^32) ----
#pragma unroll
    for (int nt = 0; nt < 4; nt++) {
        unsigned int k = key[nt];
        unsigned int o = (unsigned int)__shfl_xor((int)k, 16); k = k > o ? k : o;
        o = (unsigned int)__shfl_xor((int)k, 32);              k = k > o ? k : o;
        if (lane < 16) idxf[wv * 64 + nt * 16 + lane] = 1023 - (int)(k & 1023u);
    }
    __syncthreads();

    // ---- output: gather z_q (exact f32), write NCHW, loss partial ----
    float lsum = 0.f;
    const size_t rowbase = xbase + (size_t)wv * 64;   // h = h0 + wv
#pragma unroll
    for (int i = 0; i < 16; i++) {
        int w0 = i * 4;
        const size_t off = rowbase + (size_t)c * 4096 + w0;
        f32x4 xv = *(const f32x4*)(x + off);          // L2-hot re-read
        f32x4 ov;
#pragma unroll
        for (int j = 0; j < 4; j++) {
            int idx = idxf[wv * 64 + w0 + j];         // uniform across wave
            float zq = embed[idx * 64 + c];           // coalesced 256B row read
            ov[j] = zq;
            float d = zq - xv[j];
            lsum += d * d;
        }
        *(f32x4*)(out + off) = ov;
    }

    // ---- block-reduce loss, one atomic per block ----
#pragma unroll
    for (int o2 = 1; o2 < 64; o2 <<= 1) lsum += __shfl_xor(lsum, o2);
    if (lane == 0) lpart[wv] = lsum;
    __syncthreads();
    if (t == 0)
        atomicAdd(loss, (lpart[0] + lpart[1] + lpart[2] + lpart[3]) * LOSS_SCALE);
}

extern "C" void kernel_launch(void* const* d_in, const int* in_sizes, int n_in,
                              void* d_out, int out_size, void* d_ws, size_t ws_size,
                              hipStream_t stream) {
    const float* x     = (const float*)d_in[0];
    const float* embed = (const float*)d_in[1];
    unsigned short* eb = (unsigned short*)d_ws;               // 1024*64 bf16 = 128 KB
    float* c0          = (float*)((char*)d_ws + 131072);      // 1024 f32  = 4 KB
    float* out  = (float*)d_out;
    float* loss = out + TOTAL_ELEMS;

    vq_prep<<<16, 256, 0, stream>>>(embed, eb, c0, loss);
    vq_main<<<512, 256, 0, stream>>>(x, embed, eb, c0, out, loss);
}